// Round 3
// baseline (1318.507 us; speedup 1.0000x reference)
//
#include <hip/hip_runtime.h>

// FraudGNN: 2-layer GraphSAGE (mean agg) + fused linear classifier.
// CSR built by dst per launch (counting sort), reused by both layers.
// Aggregation: one wave per node, float4 gather, register accumulate.
// Linear layers: fused GEMM out = relu([agg|x] @ [Wl|Wr]^T + bl),
// register-blocked 8x8/thread; layer 2 fuses the classifier dot in-epilogue.

#define TPB 256

// ---- CSR build ----
__global__ void deg_count_kernel(const int* __restrict__ dst, int* __restrict__ deg, int E) {
  int i = blockIdx.x * blockDim.x + threadIdx.x;
  int stride = gridDim.x * blockDim.x;
  for (; i < E; i += stride) atomicAdd(&deg[dst[i]], 1);
}

// single-block hierarchical exclusive scan: 1024 thr x 4 elems per iter
__global__ __launch_bounds__(1024) void scan_kernel(const int* __restrict__ deg,
                                                    int* __restrict__ rowptr, int n) {
  __shared__ int wsum[16];
  int tid = threadIdx.x;
  int lane = tid & 63, wid = tid >> 6;
  int carry = 0;
  for (int base = 0; base < n; base += 4096) {
    int i0 = base + tid * 4;
    int v[4];
#pragma unroll
    for (int j = 0; j < 4; ++j) { int i = i0 + j; v[j] = (i < n) ? deg[i] : 0; }
    int s = v[0] + v[1] + v[2] + v[3];
    int ws = s;
#pragma unroll
    for (int d = 1; d < 64; d <<= 1) { int o = __shfl_up(ws, d); if (lane >= d) ws += o; }
    if (lane == 63) wsum[wid] = ws;
    __syncthreads();
    if (wid == 0 && lane < 16) {
      int t = wsum[lane];
#pragma unroll
      for (int d = 1; d < 16; d <<= 1) { int o = __shfl_up(t, d); if (lane >= d) t += o; }
      wsum[lane] = t;
    }
    __syncthreads();
    int wbase = (wid == 0) ? 0 : wsum[wid - 1];
    int run = carry + wbase + (ws - s);
#pragma unroll
    for (int j = 0; j < 4; ++j) { int i = i0 + j; if (i < n) rowptr[i] = run; run += v[j]; }
    carry += wsum[15];
    __syncthreads();
  }
  if (tid == 0) rowptr[n] = carry;
}

__global__ void aux_kernel(const int* __restrict__ deg, const int* __restrict__ rowptr,
                           int* __restrict__ cursor, float* __restrict__ rdeg, int n) {
  int i = blockIdx.x * blockDim.x + threadIdx.x;
  int stride = gridDim.x * blockDim.x;
  for (; i < n; i += stride) {
    cursor[i] = rowptr[i];
    int d = deg[i];
    rdeg[i] = 1.0f / (float)(d > 1 ? d : 1);
  }
}

__global__ void fill_kernel(const int* __restrict__ src, const int* __restrict__ dst,
                            int* __restrict__ cursor, int* __restrict__ srcs, int E) {
  int i = blockIdx.x * blockDim.x + threadIdx.x;
  int stride = gridDim.x * blockDim.x;
  for (; i < E; i += stride) {
    int d = dst[i];
    int pos = atomicAdd(&cursor[d], 1);
    srcs[pos] = src[i];
  }
}

// ---- mean aggregation: one wave per node, float4 lanes ----
// Lanes 0-31 take even edges, 32-63 odd edges; each half-wave reads a full
// 512B feature row per instruction. Combine halves via shfl_xor(32).
__global__ __launch_bounds__(256) void agg_kernel(const float* __restrict__ in,
                                                  const int* __restrict__ srcs,
                                                  const int* __restrict__ rowptr,
                                                  const float* __restrict__ rdeg,
                                                  float* __restrict__ out, int n) {
  int node = blockIdx.x * 4 + (threadIdx.x >> 6);
  if (node >= n) return;
  int lane = threadIdx.x & 63;
  int half = lane >> 5;
  int f4 = lane & 31;  // float4 index within the 128-float row
  int s0 = rowptr[node], s1 = rowptr[node + 1];
  float4 acc = {0.f, 0.f, 0.f, 0.f};
  int e = s0 + half;
  for (; e + 2 < s1; e += 4) {  // 2 edges in flight per lane
    int a = srcs[e], b = srcs[e + 2];
    float4 va = *(const float4*)(in + (size_t)a * 128 + f4 * 4);
    float4 vb = *(const float4*)(in + (size_t)b * 128 + f4 * 4);
    acc.x += va.x; acc.y += va.y; acc.z += va.z; acc.w += va.w;
    acc.x += vb.x; acc.y += vb.y; acc.z += vb.z; acc.w += vb.w;
  }
  if (e < s1) {
    float4 v = *(const float4*)(in + (size_t)srcs[e] * 128 + f4 * 4);
    acc.x += v.x; acc.y += v.y; acc.z += v.z; acc.w += v.w;
    e += 2;
  }
  if (e < s1) {
    float4 v = *(const float4*)(in + (size_t)srcs[e] * 128 + f4 * 4);
    acc.x += v.x; acc.y += v.y; acc.z += v.z; acc.w += v.w;
  }
  // combine the two halves
  acc.x += __shfl_xor(acc.x, 32);
  acc.y += __shfl_xor(acc.y, 32);
  acc.z += __shfl_xor(acc.z, 32);
  acc.w += __shfl_xor(acc.w, 32);
  if (half == 0) {
    float r = rdeg[node];
    acc.x *= r; acc.y *= r; acc.z *= r; acc.w *= r;
    *(float4*)(out + (size_t)node * 128 + f4 * 4) = acc;
  }
}

// ---- fused layer GEMM: relu([agg|x] @ [Wl|Wr]^T + bl), opt. classifier ----
// 256-row x 128-col tile per block, 512 threads, K=256 in 8 phases of 32.
// Per thread: 8 rows (rid+32i) x 8 cols (c0..c0+7) = 64 accumulators.
// A_s stride 33 -> A-read bank (rid+kk)%32, 2 lanes/bank: free.
// W_s transposed [kk][132] -> 2 distinct b128 segments per wave: free.
template <bool FUSE_CLS>
__global__ __launch_bounds__(512, 4) void sage_lin_kernel(
    const float* __restrict__ agg, const float* __restrict__ xin,
    const float* __restrict__ Wl, const float* __restrict__ bl,
    const float* __restrict__ Wr, const float* __restrict__ Wc,
    const float* __restrict__ bc, float* __restrict__ out, int n) {
  __shared__ float A_s[256 * 33];   // 33,792 B
  __shared__ float W_s[32 * 132];   // 16,896 B
  __shared__ float part[256];       // classifier partials
  int tid = threadIdx.x;
  int rid = tid & 31;
  int cg = tid >> 5;   // 0..15
  int c0 = cg * 8;
  int tile0 = blockIdx.x * 256;

  float bias[8];
#pragma unroll
  for (int j = 0; j < 8; ++j) bias[j] = bl[c0 + j];
  float acc[8][8];
#pragma unroll
  for (int i = 0; i < 8; ++i)
#pragma unroll
    for (int j = 0; j < 8; ++j) acc[i][j] = 0.f;

  for (int phase = 0; phase < 8; ++phase) {
    const float* Asrc = (phase < 4) ? agg : xin;
    const float* Wsrc = (phase < 4) ? Wl : Wr;
    int k0 = (phase & 3) * 32;
    __syncthreads();  // previous phase's LDS reads done
    // stage A tile: 256 rows x 32 k, 2048 float4 loads
    for (int f = tid; f < 2048; f += 512) {
      int row = f >> 3, kk4 = f & 7;
      int rg = tile0 + row;
      if (rg >= n) rg = n - 1;  // clamp (stores are guarded)
      float4 v = *(const float4*)(Asrc + (size_t)rg * 128 + k0 + kk4 * 4);
      float* p = &A_s[row * 33 + kk4 * 4];
      p[0] = v.x; p[1] = v.y; p[2] = v.z; p[3] = v.w;
    }
    // stage W transposed: 128 cols x 32 k, 1024 float4 loads
    for (int f = tid; f < 1024; f += 512) {
      int c = f >> 3, kk4 = f & 7;
      float4 v = *(const float4*)(Wsrc + c * 128 + k0 + kk4 * 4);
      W_s[(kk4 * 4 + 0) * 132 + c] = v.x;
      W_s[(kk4 * 4 + 1) * 132 + c] = v.y;
      W_s[(kk4 * 4 + 2) * 132 + c] = v.z;
      W_s[(kk4 * 4 + 3) * 132 + c] = v.w;
    }
    __syncthreads();
#pragma unroll
    for (int kk = 0; kk < 32; ++kk) {
      float a[8];
#pragma unroll
      for (int i = 0; i < 8; ++i) a[i] = A_s[(rid + 32 * i) * 33 + kk];
      float4 w0 = *(const float4*)&W_s[kk * 132 + c0];
      float4 w1 = *(const float4*)&W_s[kk * 132 + c0 + 4];
      float w[8] = {w0.x, w0.y, w0.z, w0.w, w1.x, w1.y, w1.z, w1.w};
#pragma unroll
      for (int i = 0; i < 8; ++i)
#pragma unroll
        for (int j = 0; j < 8; ++j) acc[i][j] += a[i] * w[j];
    }
  }

  if (FUSE_CLS) {
    // logits: out[rg] = sum_c relu(h[rg][c]) * Wc[c] + bc
    float wc[8];
#pragma unroll
    for (int j = 0; j < 8; ++j) wc[j] = Wc[c0 + j];
    if (tid < 256) part[tid] = 0.f;
    __syncthreads();
#pragma unroll
    for (int i = 0; i < 8; ++i) {
      float p = 0.f;
#pragma unroll
      for (int j = 0; j < 8; ++j) p += fmaxf(acc[i][j] + bias[j], 0.f) * wc[j];
      atomicAdd(&part[rid + 32 * i], p);
    }
    __syncthreads();
    if (tid < 256 && tile0 + tid < n) out[tile0 + tid] = part[tid] + bc[0];
  } else {
#pragma unroll
    for (int i = 0; i < 8; ++i) {
      int rg = tile0 + rid + 32 * i;
      if (rg < n) {
        float4 o0, o1;
        o0.x = fmaxf(acc[i][0] + bias[0], 0.f);
        o0.y = fmaxf(acc[i][1] + bias[1], 0.f);
        o0.z = fmaxf(acc[i][2] + bias[2], 0.f);
        o0.w = fmaxf(acc[i][3] + bias[3], 0.f);
        o1.x = fmaxf(acc[i][4] + bias[4], 0.f);
        o1.y = fmaxf(acc[i][5] + bias[5], 0.f);
        o1.z = fmaxf(acc[i][6] + bias[6], 0.f);
        o1.w = fmaxf(acc[i][7] + bias[7], 0.f);
        *(float4*)(out + (size_t)rg * 128 + c0) = o0;
        *(float4*)(out + (size_t)rg * 128 + c0 + 4) = o1;
      }
    }
  }
}

extern "C" void kernel_launch(void* const* d_in, const int* in_sizes, int n_in,
                              void* d_out, int out_size, void* d_ws, size_t ws_size,
                              hipStream_t stream) {
  const float* x   = (const float*)d_in[0];
  const int*   ei  = (const int*)d_in[1];
  const float* Wl1 = (const float*)d_in[2];
  const float* bl1 = (const float*)d_in[3];
  const float* Wr1 = (const float*)d_in[4];
  const float* Wl2 = (const float*)d_in[5];
  const float* bl2 = (const float*)d_in[6];
  const float* Wr2 = (const float*)d_in[7];
  const float* Wc  = (const float*)d_in[8];
  const float* bc  = (const float*)d_in[9];
  float* out = (float*)d_out;

  const int N = in_sizes[0] / 128;
  const int E = in_sizes[1] / 2;
  const int* src = ei;
  const int* dst = ei + E;

  // workspace carve-up (~117 MB total)
  char* w = (char*)d_ws;
  auto alloc = [&](size_t bytes) { void* p = (void*)w; w += (bytes + 255) & ~(size_t)255; return p; };
  int*   deg    = (int*)alloc((size_t)N * 4);
  int*   rowptr = (int*)alloc((size_t)(N + 1) * 4);
  int*   cursor = (int*)alloc((size_t)N * 4);
  float* rdeg   = (float*)alloc((size_t)N * 4);
  int*   srcs   = (int*)alloc((size_t)E * 4);
  float* aggbuf = (float*)alloc((size_t)N * 128 * 4);
  float* h1     = (float*)alloc((size_t)N * 128 * 4);

  // CSR build
  hipMemsetAsync(deg, 0, (size_t)N * 4, stream);
  deg_count_kernel<<<1024, TPB, 0, stream>>>(dst, deg, E);
  scan_kernel<<<1, 1024, 0, stream>>>(deg, rowptr, N);
  aux_kernel<<<(N + TPB - 1) / TPB, TPB, 0, stream>>>(deg, rowptr, cursor, rdeg, N);
  fill_kernel<<<2048, TPB, 0, stream>>>(src, dst, cursor, srcs, E);

  const int AGRID = (N + 3) / 4;
  const int LGRID = (N + 255) / 256;
  // layer 1
  agg_kernel<<<AGRID, 256, 0, stream>>>(x, srcs, rowptr, rdeg, aggbuf, N);
  sage_lin_kernel<false><<<LGRID, 512, 0, stream>>>(aggbuf, x, Wl1, bl1, Wr1,
                                                    nullptr, nullptr, h1, N);
  // layer 2 (+ fused classifier)
  agg_kernel<<<AGRID, 256, 0, stream>>>(h1, srcs, rowptr, rdeg, aggbuf, N);
  sage_lin_kernel<true><<<LGRID, 512, 0, stream>>>(aggbuf, h1, Wl2, bl2, Wr2,
                                                   Wc, bc, out, N);
}

// Round 6
// 894.174 us; speedup vs baseline: 1.4746x; 1.4746x over previous
//
#include <hip/hip_runtime.h>

// FraudGNN: 2-layer GraphSAGE (mean agg) + fused linear classifier.
// CSR built per launch via 2-pass bucketed counting sort (no global atomics,
// ~1x write amplification; a naive atomic-cursor fill showed 196MB HBM writes
// for a 12.8MB scatter = 16x partial-line writeback amplification).
// Aggregation: one wave per node, float4 gather, register accumulate.
// Linear layers: fused GEMM out = relu([agg|x] @ [Wl|Wr]^T + bl),
// register-blocked 8x8/thread; layer 2 fuses the classifier dot in-epilogue.

#define CHUNK 32768  // edges per sort block

// ---- pass 1: per-chunk bucket histogram, bucket = dst >> 8 ----
__global__ __launch_bounds__(256) void hist_kernel(const int* __restrict__ dst,
                                                   int* __restrict__ hist,
                                                   int E, int KB, int B) {
  __shared__ int h[512];
  int b = blockIdx.x, t = threadIdx.x;
  for (int k = t; k < KB; k += 256) h[k] = 0;
  __syncthreads();
  int base = b * CHUNK;
  int lim = E - base; if (lim > CHUNK) lim = CHUNK;
  const int4* d4 = (const int4*)(dst + base);
  int n4 = lim >> 2;
  for (int j = t; j < n4; j += 256) {
    int4 d = d4[j];
    atomicAdd(&h[((unsigned)d.x) >> 8], 1);
    atomicAdd(&h[((unsigned)d.y) >> 8], 1);
    atomicAdd(&h[((unsigned)d.z) >> 8], 1);
    atomicAdd(&h[((unsigned)d.w) >> 8], 1);
  }
  for (int i = (lim & ~3) + t; i < lim; i += 256)
    atomicAdd(&h[((unsigned)dst[base + i]) >> 8], 1);
  __syncthreads();
  for (int k = t; k < KB; k += 256) hist[k * B + b] = h[k];
}

// ---- scan phase A: per-1024-block sums ----
__global__ __launch_bounds__(256) void blocksum_kernel(const int* __restrict__ v,
                                                       int* __restrict__ bsum, int n) {
  __shared__ int ws[4];
  int b = blockIdx.x, t = threadIdx.x;
  int base = b * 1024;
  int s = 0;
#pragma unroll
  for (int j = 0; j < 4; ++j) {
    int i = base + t + j * 256;
    if (i < n) s += v[i];
  }
#pragma unroll
  for (int d = 32; d > 0; d >>= 1) s += __shfl_down(s, d);
  if ((t & 63) == 0) ws[t >> 6] = s;
  __syncthreads();
  if (t == 0) bsum[b] = ws[0] + ws[1] + ws[2] + ws[3];
}

// ---- scan phase B: exclusive scan of up to 128 block sums, single wave ----
__global__ __launch_bounds__(64) void scan_bsums_kernel(const int* __restrict__ bsum,
                                                        int* __restrict__ boff, int nb) {
  int l = threadIdx.x;
  int v0 = (l < nb) ? bsum[l] : 0;
  int v1 = (l + 64 < nb) ? bsum[l + 64] : 0;
  int s0 = v0, s1 = v1;
#pragma unroll
  for (int d = 1; d < 64; d <<= 1) { int o = __shfl_up(s0, d); if (l >= d) s0 += o; }
  int tot0 = __shfl(s0, 63);
#pragma unroll
  for (int d = 1; d < 64; d <<= 1) { int o = __shfl_up(s1, d); if (l >= d) s1 += o; }
  s1 += tot0;
  if (l < nb) boff[l] = s0 - v0;
  if (l + 64 < nb) boff[l + 64] = s1 - v1;
}

// ---- scan phase C: final exclusive scan ----
__global__ __launch_bounds__(1024) void finalize_scan_kernel(const int* __restrict__ v,
                                                             const int* __restrict__ boff,
                                                             int* __restrict__ off, int M) {
  __shared__ int wsum[16];
  int b = blockIdx.x, t = threadIdx.x;
  int lane = t & 63, wid = t >> 6;
  int gi = b * 1024 + t;
  int d = (gi < M) ? v[gi] : 0;
  int ws = d;
#pragma unroll
  for (int dd = 1; dd < 64; dd <<= 1) { int o = __shfl_up(ws, dd); if (lane >= dd) ws += o; }
  if (lane == 63) wsum[wid] = ws;
  __syncthreads();
  if (wid == 0 && lane < 16) {
    int x = wsum[lane];
#pragma unroll
    for (int dd = 1; dd < 16; dd <<= 1) { int o = __shfl_up(x, dd); if (lane >= dd) x += o; }
    wsum[lane] = x;
  }
  __syncthreads();
  int wbase = (wid == 0) ? 0 : wsum[wid - 1];
  if (gi < M) off[gi] = boff[b] + wbase + ws - d;
}

// ---- pass 3: scatter packed (src | dstLow<<24) into per-(block,bucket) cells ----
__global__ __launch_bounds__(256) void scatter_kernel(const int* __restrict__ src,
                                                      const int* __restrict__ dst,
                                                      const int* __restrict__ off,
                                                      int* __restrict__ buf,
                                                      int E, int KB, int B) {
  __shared__ int cur[512];
  int b = blockIdx.x, t = threadIdx.x;
  for (int k = t; k < KB; k += 256) cur[k] = off[k * B + b];
  __syncthreads();
  int base = b * CHUNK;
  int lim = E - base; if (lim > CHUNK) lim = CHUNK;
  const int4* s4 = (const int4*)(src + base);
  const int4* d4 = (const int4*)(dst + base);
  int n4 = lim >> 2;
  for (int j = t; j < n4; j += 256) {
    int4 s = s4[j];
    int4 d = d4[j];
    int p;
    p = atomicAdd(&cur[((unsigned)d.x) >> 8], 1); buf[p] = s.x | ((d.x & 255) << 24);
    p = atomicAdd(&cur[((unsigned)d.y) >> 8], 1); buf[p] = s.y | ((d.y & 255) << 24);
    p = atomicAdd(&cur[((unsigned)d.z) >> 8], 1); buf[p] = s.z | ((d.z & 255) << 24);
    p = atomicAdd(&cur[((unsigned)d.w) >> 8], 1); buf[p] = s.w | ((d.w & 255) << 24);
  }
  for (int i = (lim & ~3) + t; i < lim; i += 256) {
    int s = src[base + i], d = dst[base + i];
    int p = atomicAdd(&cur[((unsigned)d) >> 8], 1);
    buf[p] = s | ((d & 255) << 24);
  }
}

// ---- pass 4: per-bucket counting sort in LDS; writes rowptr/rdeg + sorted srcs ----
// stage = 48KB so total static LDS (50KB) stays under the 64KB/WG limit.
// Bucket size ~ Binomial(E, 256/N): mean 8192, sigma ~90 -> 12288 = mean+45sig.
__global__ __launch_bounds__(256) void bucket_kernel(const int* __restrict__ off,
                                                     int* __restrict__ buf,
                                                     int* __restrict__ rowptr,
                                                     float* __restrict__ rdeg,
                                                     int N, int E, int KB, int B) {
  __shared__ int stage[12288];
  __shared__ int cnt[256], cur2[256];
  int k = blockIdx.x, t = threadIdx.x;
  int lo = off[k * B];
  int hi = (k == KB - 1) ? E : off[(k + 1) * B];
  int m = hi - lo; if (m > 12288) m = 12288;  // statistically unreachable
  for (int i = t; i < m; i += 256) stage[i] = buf[lo + i];
  cnt[t] = 0;
  __syncthreads();
  for (int i = t; i < m; i += 256) atomicAdd(&cnt[((unsigned)stage[i]) >> 24], 1);
  __syncthreads();
  if (t < 64) {
    int c[4], e[4];
    int i0 = t * 4;
    c[0] = cnt[i0]; c[1] = cnt[i0 + 1]; c[2] = cnt[i0 + 2]; c[3] = cnt[i0 + 3];
    int local = c[0] + c[1] + c[2] + c[3];
    int ws = local;
#pragma unroll
    for (int d = 1; d < 64; d <<= 1) { int o = __shfl_up(ws, d); if (t >= d) ws += o; }
    e[0] = ws - local;
    e[1] = e[0] + c[0];
    e[2] = e[1] + c[1];
    e[3] = e[2] + c[2];
#pragma unroll
    for (int j = 0; j < 4; ++j) {
      cur2[i0 + j] = e[j];
      int node = k * 256 + i0 + j;
      if (node < N) {
        rowptr[node] = lo + e[j];
        rdeg[node] = 1.0f / (float)(c[j] > 1 ? c[j] : 1);
      }
    }
  }
  __syncthreads();
  for (int i = t; i < m; i += 256) {
    int v = stage[i];
    int d = ((unsigned)v) >> 24;
    int p = atomicAdd(&cur2[d], 1);
    buf[lo + p] = v & 0xFFFFFF;
  }
  if (k == 0 && t == 0) rowptr[N] = E;
}

// ---- mean aggregation: one wave per node, float4 lanes ----
__global__ __launch_bounds__(256) void agg_kernel(const float* __restrict__ in,
                                                  const int* __restrict__ srcs,
                                                  const int* __restrict__ rowptr,
                                                  const float* __restrict__ rdeg,
                                                  float* __restrict__ out, int n) {
  int node = blockIdx.x * 4 + (threadIdx.x >> 6);
  if (node >= n) return;
  int lane = threadIdx.x & 63;
  int half = lane >> 5;
  int f4 = lane & 31;  // float4 index within the 128-float row
  int s0 = rowptr[node], s1 = rowptr[node + 1];
  float4 acc = {0.f, 0.f, 0.f, 0.f};
  int e = s0 + half;
  for (; e + 2 < s1; e += 4) {  // 2 edges in flight per lane
    int a = srcs[e], b = srcs[e + 2];
    float4 va = *(const float4*)(in + (size_t)a * 128 + f4 * 4);
    float4 vb = *(const float4*)(in + (size_t)b * 128 + f4 * 4);
    acc.x += va.x; acc.y += va.y; acc.z += va.z; acc.w += va.w;
    acc.x += vb.x; acc.y += vb.y; acc.z += vb.z; acc.w += vb.w;
  }
  if (e < s1) {
    float4 v = *(const float4*)(in + (size_t)srcs[e] * 128 + f4 * 4);
    acc.x += v.x; acc.y += v.y; acc.z += v.z; acc.w += v.w;
    e += 2;
  }
  if (e < s1) {
    float4 v = *(const float4*)(in + (size_t)srcs[e] * 128 + f4 * 4);
    acc.x += v.x; acc.y += v.y; acc.z += v.z; acc.w += v.w;
  }
  acc.x += __shfl_xor(acc.x, 32);
  acc.y += __shfl_xor(acc.y, 32);
  acc.z += __shfl_xor(acc.z, 32);
  acc.w += __shfl_xor(acc.w, 32);
  if (half == 0) {
    float r = rdeg[node];
    acc.x *= r; acc.y *= r; acc.z *= r; acc.w *= r;
    *(float4*)(out + (size_t)node * 128 + f4 * 4) = acc;
  }
}

// ---- fused layer GEMM: relu([agg|x] @ [Wl|Wr]^T + bl), opt. classifier ----
// 256-row x 128-col tile per block, 512 threads, K=256 in 8 phases of 32.
// Per thread: 8 rows (rid+32i) x 8 cols (c0..c0+7) = 64 accumulators.
// NOTE: no min-blocks arg in launch_bounds — a (512,4) variant capped VGPRs
// at 64 and spilled all 64 accumulators to scratch (FETCH 310MB/WRITE 552MB).
template <bool FUSE_CLS>
__global__ __launch_bounds__(512) void sage_lin_kernel(
    const float* __restrict__ agg, const float* __restrict__ xin,
    const float* __restrict__ Wl, const float* __restrict__ bl,
    const float* __restrict__ Wr, const float* __restrict__ Wc,
    const float* __restrict__ bc, float* __restrict__ out, int n) {
  __shared__ float A_s[256 * 33];   // 33,792 B
  __shared__ float W_s[32 * 132];   // 16,896 B
  __shared__ float part[256];       // classifier partials
  int tid = threadIdx.x;
  int rid = tid & 31;
  int cg = tid >> 5;   // 0..15
  int c0 = cg * 8;
  int tile0 = blockIdx.x * 256;

  float bias[8];
#pragma unroll
  for (int j = 0; j < 8; ++j) bias[j] = bl[c0 + j];
  float acc[8][8];
#pragma unroll
  for (int i = 0; i < 8; ++i)
#pragma unroll
    for (int j = 0; j < 8; ++j) acc[i][j] = 0.f;

  for (int phase = 0; phase < 8; ++phase) {
    const float* Asrc = (phase < 4) ? agg : xin;
    const float* Wsrc = (phase < 4) ? Wl : Wr;
    int k0 = (phase & 3) * 32;
    __syncthreads();  // previous phase's LDS reads done
    // stage A tile: 256 rows x 32 k, 2048 float4 loads
    for (int f = tid; f < 2048; f += 512) {
      int row = f >> 3, kk4 = f & 7;
      int rg = tile0 + row;
      if (rg >= n) rg = n - 1;  // clamp (stores are guarded)
      float4 v = *(const float4*)(Asrc + (size_t)rg * 128 + k0 + kk4 * 4);
      float* p = &A_s[row * 33 + kk4 * 4];
      p[0] = v.x; p[1] = v.y; p[2] = v.z; p[3] = v.w;
    }
    // stage W transposed: 128 cols x 32 k, 1024 float4 loads
    for (int f = tid; f < 1024; f += 512) {
      int c = f >> 3, kk4 = f & 7;
      float4 v = *(const float4*)(Wsrc + c * 128 + k0 + kk4 * 4);
      W_s[(kk4 * 4 + 0) * 132 + c] = v.x;
      W_s[(kk4 * 4 + 1) * 132 + c] = v.y;
      W_s[(kk4 * 4 + 2) * 132 + c] = v.z;
      W_s[(kk4 * 4 + 3) * 132 + c] = v.w;
    }
    __syncthreads();
#pragma unroll
    for (int kk = 0; kk < 32; ++kk) {
      float a[8];
#pragma unroll
      for (int i = 0; i < 8; ++i) a[i] = A_s[(rid + 32 * i) * 33 + kk];
      float4 w0 = *(const float4*)&W_s[kk * 132 + c0];
      float4 w1 = *(const float4*)&W_s[kk * 132 + c0 + 4];
      float w[8] = {w0.x, w0.y, w0.z, w0.w, w1.x, w1.y, w1.z, w1.w};
#pragma unroll
      for (int i = 0; i < 8; ++i)
#pragma unroll
        for (int j = 0; j < 8; ++j) acc[i][j] += a[i] * w[j];
    }
  }

  if (FUSE_CLS) {
    // logits: out[rg] = sum_c relu(h[rg][c]) * Wc[c] + bc
    float wc[8];
#pragma unroll
    for (int j = 0; j < 8; ++j) wc[j] = Wc[c0 + j];
    if (tid < 256) part[tid] = 0.f;
    __syncthreads();
#pragma unroll
    for (int i = 0; i < 8; ++i) {
      float p = 0.f;
#pragma unroll
      for (int j = 0; j < 8; ++j) p += fmaxf(acc[i][j] + bias[j], 0.f) * wc[j];
      atomicAdd(&part[rid + 32 * i], p);
    }
    __syncthreads();
    if (tid < 256 && tile0 + tid < n) out[tile0 + tid] = part[tid] + bc[0];
  } else {
#pragma unroll
    for (int i = 0; i < 8; ++i) {
      int rg = tile0 + rid + 32 * i;
      if (rg < n) {
        float4 o0, o1;
        o0.x = fmaxf(acc[i][0] + bias[0], 0.f);
        o0.y = fmaxf(acc[i][1] + bias[1], 0.f);
        o0.z = fmaxf(acc[i][2] + bias[2], 0.f);
        o0.w = fmaxf(acc[i][3] + bias[3], 0.f);
        o1.x = fmaxf(acc[i][4] + bias[4], 0.f);
        o1.y = fmaxf(acc[i][5] + bias[5], 0.f);
        o1.z = fmaxf(acc[i][6] + bias[6], 0.f);
        o1.w = fmaxf(acc[i][7] + bias[7], 0.f);
        *(float4*)(out + (size_t)rg * 128 + c0) = o0;
        *(float4*)(out + (size_t)rg * 128 + c0 + 4) = o1;
      }
    }
  }
}

extern "C" void kernel_launch(void* const* d_in, const int* in_sizes, int n_in,
                              void* d_out, int out_size, void* d_ws, size_t ws_size,
                              hipStream_t stream) {
  const float* x   = (const float*)d_in[0];
  const int*   ei  = (const int*)d_in[1];
  const float* Wl1 = (const float*)d_in[2];
  const float* bl1 = (const float*)d_in[3];
  const float* Wr1 = (const float*)d_in[4];
  const float* Wl2 = (const float*)d_in[5];
  const float* bl2 = (const float*)d_in[6];
  const float* Wr2 = (const float*)d_in[7];
  const float* Wc  = (const float*)d_in[8];
  const float* bc  = (const float*)d_in[9];
  float* out = (float*)d_out;

  const int N = in_sizes[0] / 128;
  const int E = in_sizes[1] / 2;
  const int* src = ei;
  const int* dst = ei + E;

  const int KB = (N + 255) >> 8;            // buckets (391)
  const int B  = (E + CHUNK - 1) / CHUNK;   // sort blocks (98)
  const int M  = KB * B;                    // histogram cells (38318)
  const int NB = (M + 1023) / 1024;         // scan blocks (38)

  // workspace carve-up (~116 MB total)
  char* w = (char*)d_ws;
  auto alloc = [&](size_t bytes) { void* p = (void*)w; w += (bytes + 255) & ~(size_t)255; return p; };
  int*   hist   = (int*)alloc((size_t)M * 4);
  int*   off    = (int*)alloc((size_t)M * 4);
  int*   bsum   = (int*)alloc((size_t)NB * 4);
  int*   boff   = (int*)alloc((size_t)NB * 4);
  int*   buf    = (int*)alloc((size_t)E * 4);       // packed, then sorted srcs
  int*   rowptr = (int*)alloc((size_t)(N + 1) * 4);
  float* rdeg   = (float*)alloc((size_t)N * 4);
  float* aggbuf = (float*)alloc((size_t)N * 128 * 4);
  float* h1     = (float*)alloc((size_t)N * 128 * 4);

  // CSR build (bucketed counting sort, no global atomics)
  hist_kernel<<<B, 256, 0, stream>>>(dst, hist, E, KB, B);
  blocksum_kernel<<<NB, 256, 0, stream>>>(hist, bsum, M);
  scan_bsums_kernel<<<1, 64, 0, stream>>>(bsum, boff, NB);
  finalize_scan_kernel<<<NB, 1024, 0, stream>>>(hist, boff, off, M);
  scatter_kernel<<<B, 256, 0, stream>>>(src, dst, off, buf, E, KB, B);
  bucket_kernel<<<KB, 256, 0, stream>>>(off, buf, rowptr, rdeg, N, E, KB, B);

  const int AGRID = (N + 3) / 4;
  const int LGRID = (N + 255) / 256;
  // layer 1
  agg_kernel<<<AGRID, 256, 0, stream>>>(x, buf, rowptr, rdeg, aggbuf, N);
  sage_lin_kernel<false><<<LGRID, 512, 0, stream>>>(aggbuf, x, Wl1, bl1, Wr1,
                                                    nullptr, nullptr, h1, N);
  // layer 2 (+ fused classifier)
  agg_kernel<<<AGRID, 256, 0, stream>>>(h1, buf, rowptr, rdeg, aggbuf, N);
  sage_lin_kernel<true><<<LGRID, 512, 0, stream>>>(aggbuf, h1, Wl2, bl2, Wr2,
                                                   Wc, bc, out, N);
}

// Round 8
// 711.816 us; speedup vs baseline: 1.8523x; 1.2562x over previous
//
#include <hip/hip_runtime.h>

// FraudGNN: 2-layer GraphSAGE (mean agg) + fused linear classifier.
// CSR built per launch via 2-pass bucketed counting sort (no global atomics).
// Aggregation: gathers from a bf16 (RNE) copy of the features — halves the
// random-gather traffic (f32 agg showed FETCH=751MB/disp @3.85TB/s eff).
// Linear layers keep full f32 GEMM: relu([agg|x] @ [Wl|Wr]^T + bl),
// register-blocked 8x8/thread; layer 2 fuses the classifier dot in-epilogue.

#define CHUNK 32768  // edges per sort block

__device__ __forceinline__ unsigned bf16rne(float f) {
  unsigned u = __float_as_uint(f);
  return (u + 0x7fffu + ((u >> 16) & 1u)) >> 16;
}

// ---- pass 1: per-chunk bucket histogram, bucket = dst >> 8 ----
__global__ __launch_bounds__(256) void hist_kernel(const int* __restrict__ dst,
                                                   int* __restrict__ hist,
                                                   int E, int KB, int B) {
  __shared__ int h[512];
  int b = blockIdx.x, t = threadIdx.x;
  for (int k = t; k < KB; k += 256) h[k] = 0;
  __syncthreads();
  int base = b * CHUNK;
  int lim = E - base; if (lim > CHUNK) lim = CHUNK;
  const int4* d4 = (const int4*)(dst + base);
  int n4 = lim >> 2;
  for (int j = t; j < n4; j += 256) {
    int4 d = d4[j];
    atomicAdd(&h[((unsigned)d.x) >> 8], 1);
    atomicAdd(&h[((unsigned)d.y) >> 8], 1);
    atomicAdd(&h[((unsigned)d.z) >> 8], 1);
    atomicAdd(&h[((unsigned)d.w) >> 8], 1);
  }
  for (int i = (lim & ~3) + t; i < lim; i += 256)
    atomicAdd(&h[((unsigned)dst[base + i]) >> 8], 1);
  __syncthreads();
  for (int k = t; k < KB; k += 256) hist[k * B + b] = h[k];
}

// ---- scan phase A: per-1024-block sums ----
__global__ __launch_bounds__(256) void blocksum_kernel(const int* __restrict__ v,
                                                       int* __restrict__ bsum, int n) {
  __shared__ int ws[4];
  int b = blockIdx.x, t = threadIdx.x;
  int base = b * 1024;
  int s = 0;
#pragma unroll
  for (int j = 0; j < 4; ++j) {
    int i = base + t + j * 256;
    if (i < n) s += v[i];
  }
#pragma unroll
  for (int d = 32; d > 0; d >>= 1) s += __shfl_down(s, d);
  if ((t & 63) == 0) ws[t >> 6] = s;
  __syncthreads();
  if (t == 0) bsum[b] = ws[0] + ws[1] + ws[2] + ws[3];
}

// ---- scan phase B: exclusive scan of up to 128 block sums, single wave ----
__global__ __launch_bounds__(64) void scan_bsums_kernel(const int* __restrict__ bsum,
                                                        int* __restrict__ boff, int nb) {
  int l = threadIdx.x;
  int v0 = (l < nb) ? bsum[l] : 0;
  int v1 = (l + 64 < nb) ? bsum[l + 64] : 0;
  int s0 = v0, s1 = v1;
#pragma unroll
  for (int d = 1; d < 64; d <<= 1) { int o = __shfl_up(s0, d); if (l >= d) s0 += o; }
  int tot0 = __shfl(s0, 63);
#pragma unroll
  for (int d = 1; d < 64; d <<= 1) { int o = __shfl_up(s1, d); if (l >= d) s1 += o; }
  s1 += tot0;
  if (l < nb) boff[l] = s0 - v0;
  if (l + 64 < nb) boff[l + 64] = s1 - v1;
}

// ---- scan phase C: final exclusive scan ----
__global__ __launch_bounds__(1024) void finalize_scan_kernel(const int* __restrict__ v,
                                                             const int* __restrict__ boff,
                                                             int* __restrict__ off, int M) {
  __shared__ int wsum[16];
  int b = blockIdx.x, t = threadIdx.x;
  int lane = t & 63, wid = t >> 6;
  int gi = b * 1024 + t;
  int d = (gi < M) ? v[gi] : 0;
  int ws = d;
#pragma unroll
  for (int dd = 1; dd < 64; dd <<= 1) { int o = __shfl_up(ws, dd); if (lane >= dd) ws += o; }
  if (lane == 63) wsum[wid] = ws;
  __syncthreads();
  if (wid == 0 && lane < 16) {
    int x = wsum[lane];
#pragma unroll
    for (int dd = 1; dd < 16; dd <<= 1) { int o = __shfl_up(x, dd); if (lane >= dd) x += o; }
    wsum[lane] = x;
  }
  __syncthreads();
  int wbase = (wid == 0) ? 0 : wsum[wid - 1];
  if (gi < M) off[gi] = boff[b] + wbase + ws - d;
}

// ---- pass 3: scatter packed (src | dstLow<<24) into per-(block,bucket) cells ----
__global__ __launch_bounds__(256) void scatter_kernel(const int* __restrict__ src,
                                                      const int* __restrict__ dst,
                                                      const int* __restrict__ off,
                                                      int* __restrict__ buf,
                                                      int E, int KB, int B) {
  __shared__ int cur[512];
  int b = blockIdx.x, t = threadIdx.x;
  for (int k = t; k < KB; k += 256) cur[k] = off[k * B + b];
  __syncthreads();
  int base = b * CHUNK;
  int lim = E - base; if (lim > CHUNK) lim = CHUNK;
  const int4* s4 = (const int4*)(src + base);
  const int4* d4 = (const int4*)(dst + base);
  int n4 = lim >> 2;
  for (int j = t; j < n4; j += 256) {
    int4 s = s4[j];
    int4 d = d4[j];
    int p;
    p = atomicAdd(&cur[((unsigned)d.x) >> 8], 1); buf[p] = s.x | ((d.x & 255) << 24);
    p = atomicAdd(&cur[((unsigned)d.y) >> 8], 1); buf[p] = s.y | ((d.y & 255) << 24);
    p = atomicAdd(&cur[((unsigned)d.z) >> 8], 1); buf[p] = s.z | ((d.z & 255) << 24);
    p = atomicAdd(&cur[((unsigned)d.w) >> 8], 1); buf[p] = s.w | ((d.w & 255) << 24);
  }
  for (int i = (lim & ~3) + t; i < lim; i += 256) {
    int s = src[base + i], d = dst[base + i];
    int p = atomicAdd(&cur[((unsigned)d) >> 8], 1);
    buf[p] = s | ((d & 255) << 24);
  }
}

// ---- pass 4: per-bucket counting sort in LDS; writes rowptr/rdeg + sorted srcs ----
// stage = 48KB so total static LDS (50KB) stays under the 64KB/WG limit.
// Bucket size ~ Binomial(E, 256/N): mean 8192, sigma ~90 -> 12288 = mean+45sig.
__global__ __launch_bounds__(256) void bucket_kernel(const int* __restrict__ off,
                                                     int* __restrict__ buf,
                                                     int* __restrict__ rowptr,
                                                     float* __restrict__ rdeg,
                                                     int N, int E, int KB, int B) {
  __shared__ int stage[12288];
  __shared__ int cnt[256], cur2[256];
  int k = blockIdx.x, t = threadIdx.x;
  int lo = off[k * B];
  int hi = (k == KB - 1) ? E : off[(k + 1) * B];
  int m = hi - lo; if (m > 12288) m = 12288;  // statistically unreachable
  for (int i = t; i < m; i += 256) stage[i] = buf[lo + i];
  cnt[t] = 0;
  __syncthreads();
  for (int i = t; i < m; i += 256) atomicAdd(&cnt[((unsigned)stage[i]) >> 24], 1);
  __syncthreads();
  if (t < 64) {
    int c[4], e[4];
    int i0 = t * 4;
    c[0] = cnt[i0]; c[1] = cnt[i0 + 1]; c[2] = cnt[i0 + 2]; c[3] = cnt[i0 + 3];
    int local = c[0] + c[1] + c[2] + c[3];
    int ws = local;
#pragma unroll
    for (int d = 1; d < 64; d <<= 1) { int o = __shfl_up(ws, d); if (t >= d) ws += o; }
    e[0] = ws - local;
    e[1] = e[0] + c[0];
    e[2] = e[1] + c[1];
    e[3] = e[2] + c[2];
#pragma unroll
    for (int j = 0; j < 4; ++j) {
      cur2[i0 + j] = e[j];
      int node = k * 256 + i0 + j;
      if (node < N) {
        rowptr[node] = lo + e[j];
        rdeg[node] = 1.0f / (float)(c[j] > 1 ? c[j] : 1);
      }
    }
  }
  __syncthreads();
  for (int i = t; i < m; i += 256) {
    int v = stage[i];
    int d = ((unsigned)v) >> 24;
    int p = atomicAdd(&cur2[d], 1);
    buf[lo + p] = v & 0xFFFFFF;
  }
  if (k == 0 && t == 0) rowptr[N] = E;
}

// ---- f32 -> bf16 (RNE) conversion, 8 elems/thread ----
__global__ __launch_bounds__(256) void conv_kernel(const float* __restrict__ in,
                                                   unsigned short* __restrict__ out,
                                                   int n8) {  // n/8
  int i = blockIdx.x * blockDim.x + threadIdx.x;
  int stride = gridDim.x * blockDim.x;
  for (; i < n8; i += stride) {
    float4 a = ((const float4*)in)[i * 2];
    float4 b = ((const float4*)in)[i * 2 + 1];
    int4 o;
    o.x = (int)(bf16rne(a.x) | (bf16rne(a.y) << 16));
    o.y = (int)(bf16rne(a.z) | (bf16rne(a.w) << 16));
    o.z = (int)(bf16rne(b.x) | (bf16rne(b.y) << 16));
    o.w = (int)(bf16rne(b.z) | (bf16rne(b.w) << 16));
    ((int4*)out)[i] = o;
  }
}

// ---- mean aggregation from bf16 rows: one wave per node ----
// 16-lane groups: lane = g*16+f; group g takes edges e ≡ g (mod 4),
// lane f loads int4 = 8 bf16 features (f*8..f*8+7). 2-deep unroll -> 8 edges
// in flight per wave. Group-reduce via shfl_xor(16/32); lanes 0-15 write f32.
__global__ __launch_bounds__(256) void agg_kernel(const unsigned short* __restrict__ inb,
                                                  const int* __restrict__ srcs,
                                                  const int* __restrict__ rowptr,
                                                  const float* __restrict__ rdeg,
                                                  float* __restrict__ out, int n) {
  int node = blockIdx.x * 4 + (threadIdx.x >> 6);
  if (node >= n) return;
  int lane = threadIdx.x & 63;
  int g = lane >> 4;
  int f = lane & 15;
  int s0 = rowptr[node], s1 = rowptr[node + 1];
  float acc[8];
#pragma unroll
  for (int j = 0; j < 8; ++j) acc[j] = 0.f;

  int e = s0 + g;
  for (; e + 4 < s1; e += 8) {
    int a = srcs[e], b = srcs[e + 4];
    int4 va = ((const int4*)(inb + (size_t)a * 128))[f];
    int4 vb = ((const int4*)(inb + (size_t)b * 128))[f];
#pragma unroll
    for (int j = 0; j < 4; ++j) {
      int w = (&va.x)[j];
      acc[j * 2]     += __uint_as_float(((unsigned)w) << 16);
      acc[j * 2 + 1] += __uint_as_float(((unsigned)w) & 0xffff0000u);
    }
#pragma unroll
    for (int j = 0; j < 4; ++j) {
      int w = (&vb.x)[j];
      acc[j * 2]     += __uint_as_float(((unsigned)w) << 16);
      acc[j * 2 + 1] += __uint_as_float(((unsigned)w) & 0xffff0000u);
    }
  }
  if (e < s1) {
    int4 v = ((const int4*)(inb + (size_t)srcs[e] * 128))[f];
#pragma unroll
    for (int j = 0; j < 4; ++j) {
      int w = (&v.x)[j];
      acc[j * 2]     += __uint_as_float(((unsigned)w) << 16);
      acc[j * 2 + 1] += __uint_as_float(((unsigned)w) & 0xffff0000u);
    }
  }
  // reduce across the 4 groups
#pragma unroll
  for (int j = 0; j < 8; ++j) {
    acc[j] += __shfl_xor(acc[j], 16);
    acc[j] += __shfl_xor(acc[j], 32);
  }
  if (lane < 16) {
    float r = rdeg[node];
    float4 o0 = {acc[0] * r, acc[1] * r, acc[2] * r, acc[3] * r};
    float4 o1 = {acc[4] * r, acc[5] * r, acc[6] * r, acc[7] * r};
    float* op = out + (size_t)node * 128 + f * 8;
    *(float4*)op = o0;
    *(float4*)(op + 4) = o1;
  }
}

// ---- fused layer GEMM: relu([agg|x] @ [Wl|Wr]^T + bl) ----
// 256-row x 128-col tile per block, 512 threads, K=256 in 8 phases of 32.
// Per thread: 8 rows (rid+32i) x 8 cols (c0..c0+7) = 64 accumulators.
// outb (if non-null): bf16 copy of the relu output (next layer's agg source).
// FUSE_CLS: classifier dot folded into the epilogue instead of storing h.
// NOTE: no min-blocks arg in launch_bounds — a (512,4) variant capped VGPRs
// at 64 and spilled all 64 accumulators to scratch (FETCH 310MB/WRITE 552MB).
template <bool FUSE_CLS>
__global__ __launch_bounds__(512) void sage_lin_kernel(
    const float* __restrict__ agg, const float* __restrict__ xin,
    const float* __restrict__ Wl, const float* __restrict__ bl,
    const float* __restrict__ Wr, const float* __restrict__ Wc,
    const float* __restrict__ bc, float* __restrict__ out,
    unsigned short* __restrict__ outb, int n) {
  __shared__ float A_s[256 * 33];   // 33,792 B
  __shared__ float W_s[32 * 132];   // 16,896 B
  __shared__ float part[256];       // classifier partials
  int tid = threadIdx.x;
  int rid = tid & 31;
  int cg = tid >> 5;   // 0..15
  int c0 = cg * 8;
  int tile0 = blockIdx.x * 256;

  float bias[8];
#pragma unroll
  for (int j = 0; j < 8; ++j) bias[j] = bl[c0 + j];
  float acc[8][8];
#pragma unroll
  for (int i = 0; i < 8; ++i)
#pragma unroll
    for (int j = 0; j < 8; ++j) acc[i][j] = 0.f;

  for (int phase = 0; phase < 8; ++phase) {
    const float* Asrc = (phase < 4) ? agg : xin;
    const float* Wsrc = (phase < 4) ? Wl : Wr;
    int k0 = (phase & 3) * 32;
    __syncthreads();  // previous phase's LDS reads done
    // stage A tile: 256 rows x 32 k, 2048 float4 loads
    for (int fi = tid; fi < 2048; fi += 512) {
      int row = fi >> 3, kk4 = fi & 7;
      int rg = tile0 + row;
      if (rg >= n) rg = n - 1;  // clamp (stores are guarded)
      float4 v = *(const float4*)(Asrc + (size_t)rg * 128 + k0 + kk4 * 4);
      float* p = &A_s[row * 33 + kk4 * 4];
      p[0] = v.x; p[1] = v.y; p[2] = v.z; p[3] = v.w;
    }
    // stage W transposed: 128 cols x 32 k, 1024 float4 loads
    for (int fi = tid; fi < 1024; fi += 512) {
      int c = fi >> 3, kk4 = fi & 7;
      float4 v = *(const float4*)(Wsrc + c * 128 + k0 + kk4 * 4);
      W_s[(kk4 * 4 + 0) * 132 + c] = v.x;
      W_s[(kk4 * 4 + 1) * 132 + c] = v.y;
      W_s[(kk4 * 4 + 2) * 132 + c] = v.z;
      W_s[(kk4 * 4 + 3) * 132 + c] = v.w;
    }
    __syncthreads();
#pragma unroll
    for (int kk = 0; kk < 32; ++kk) {
      float a[8];
#pragma unroll
      for (int i = 0; i < 8; ++i) a[i] = A_s[(rid + 32 * i) * 33 + kk];
      float4 w0 = *(const float4*)&W_s[kk * 132 + c0];
      float4 w1 = *(const float4*)&W_s[kk * 132 + c0 + 4];
#pragma unroll
      for (int i = 0; i < 8; ++i) {
        acc[i][0] += a[i] * w0.x;
        acc[i][1] += a[i] * w0.y;
        acc[i][2] += a[i] * w0.z;
        acc[i][3] += a[i] * w0.w;
        acc[i][4] += a[i] * w1.x;
        acc[i][5] += a[i] * w1.y;
        acc[i][6] += a[i] * w1.z;
        acc[i][7] += a[i] * w1.w;
      }
    }
  }

  if (FUSE_CLS) {
    // logits: out[rg] = sum_c relu(h[rg][c]) * Wc[c] + bc
    float wc[8];
#pragma unroll
    for (int j = 0; j < 8; ++j) wc[j] = Wc[c0 + j];
    if (tid < 256) part[tid] = 0.f;
    __syncthreads();
#pragma unroll
    for (int i = 0; i < 8; ++i) {
      float p = 0.f;
#pragma unroll
      for (int j = 0; j < 8; ++j) p += fmaxf(acc[i][j] + bias[j], 0.f) * wc[j];
      atomicAdd(&part[rid + 32 * i], p);
    }
    __syncthreads();
    if (tid < 256 && tile0 + tid < n) out[tile0 + tid] = part[tid] + bc[0];
  } else {
#pragma unroll
    for (int i = 0; i < 8; ++i) {
      int rg = tile0 + rid + 32 * i;
      if (rg < n) {
        float4 o0, o1;
        o0.x = fmaxf(acc[i][0] + bias[0], 0.f);
        o0.y = fmaxf(acc[i][1] + bias[1], 0.f);
        o0.z = fmaxf(acc[i][2] + bias[2], 0.f);
        o0.w = fmaxf(acc[i][3] + bias[3], 0.f);
        o1.x = fmaxf(acc[i][4] + bias[4], 0.f);
        o1.y = fmaxf(acc[i][5] + bias[5], 0.f);
        o1.z = fmaxf(acc[i][6] + bias[6], 0.f);
        o1.w = fmaxf(acc[i][7] + bias[7], 0.f);
        *(float4*)(out + (size_t)rg * 128 + c0) = o0;
        *(float4*)(out + (size_t)rg * 128 + c0 + 4) = o1;
        int4 ob;
        ob.x = (int)(bf16rne(o0.x) | (bf16rne(o0.y) << 16));
        ob.y = (int)(bf16rne(o0.z) | (bf16rne(o0.w) << 16));
        ob.z = (int)(bf16rne(o1.x) | (bf16rne(o1.y) << 16));
        ob.w = (int)(bf16rne(o1.z) | (bf16rne(o1.w) << 16));
        *(int4*)(outb + (size_t)rg * 128 + c0) = ob;
      }
    }
  }
}

extern "C" void kernel_launch(void* const* d_in, const int* in_sizes, int n_in,
                              void* d_out, int out_size, void* d_ws, size_t ws_size,
                              hipStream_t stream) {
  const float* x   = (const float*)d_in[0];
  const int*   ei  = (const int*)d_in[1];
  const float* Wl1 = (const float*)d_in[2];
  const float* bl1 = (const float*)d_in[3];
  const float* Wr1 = (const float*)d_in[4];
  const float* Wl2 = (const float*)d_in[5];
  const float* bl2 = (const float*)d_in[6];
  const float* Wr2 = (const float*)d_in[7];
  const float* Wc  = (const float*)d_in[8];
  const float* bc  = (const float*)d_in[9];
  float* out = (float*)d_out;

  const int N = in_sizes[0] / 128;
  const int E = in_sizes[1] / 2;
  const int* src = ei;
  const int* dst = ei + E;

  const int KB = (N + 255) >> 8;            // buckets (391)
  const int B  = (E + CHUNK - 1) / CHUNK;   // sort blocks (98)
  const int M  = KB * B;                    // histogram cells (38318)
  const int NB = (M + 1023) / 1024;         // scan blocks (38)

  // workspace carve-up (~143 MB total)
  char* w = (char*)d_ws;
  auto alloc = [&](size_t bytes) { void* p = (void*)w; w += (bytes + 255) & ~(size_t)255; return p; };
  int*   hist   = (int*)alloc((size_t)M * 4);
  int*   off    = (int*)alloc((size_t)M * 4);
  int*   bsum   = (int*)alloc((size_t)NB * 4);
  int*   boff   = (int*)alloc((size_t)NB * 4);
  int*   buf    = (int*)alloc((size_t)E * 4);       // packed, then sorted srcs
  int*   rowptr = (int*)alloc((size_t)(N + 1) * 4);
  float* rdeg   = (float*)alloc((size_t)N * 4);
  unsigned short* xb  = (unsigned short*)alloc((size_t)N * 128 * 2);
  unsigned short* h1b = (unsigned short*)alloc((size_t)N * 128 * 2);
  float* aggbuf = (float*)alloc((size_t)N * 128 * 4);
  float* h1     = (float*)alloc((size_t)N * 128 * 4);

  // CSR build (bucketed counting sort, no global atomics)
  hist_kernel<<<B, 256, 0, stream>>>(dst, hist, E, KB, B);
  blocksum_kernel<<<NB, 256, 0, stream>>>(hist, bsum, M);
  scan_bsums_kernel<<<1, 64, 0, stream>>>(bsum, boff, NB);
  finalize_scan_kernel<<<NB, 1024, 0, stream>>>(hist, boff, off, M);
  scatter_kernel<<<B, 256, 0, stream>>>(src, dst, off, buf, E, KB, B);
  bucket_kernel<<<KB, 256, 0, stream>>>(off, buf, rowptr, rdeg, N, E, KB, B);
  // bf16 gather copy of x (overlaps with sort on other CUs)
  conv_kernel<<<1024, 256, 0, stream>>>(x, xb, N * 128 / 8);

  const int AGRID = (N + 3) / 4;
  const int LGRID = (N + 255) / 256;
  // layer 1
  agg_kernel<<<AGRID, 256, 0, stream>>>(xb, buf, rowptr, rdeg, aggbuf, N);
  sage_lin_kernel<false><<<LGRID, 512, 0, stream>>>(aggbuf, x, Wl1, bl1, Wr1,
                                                    nullptr, nullptr, h1, h1b, N);
  // layer 2 (+ fused classifier)
  agg_kernel<<<AGRID, 256, 0, stream>>>(h1b, buf, rowptr, rdeg, aggbuf, N);
  sage_lin_kernel<true><<<LGRID, 512, 0, stream>>>(aggbuf, h1, Wl2, bl2, Wr2,
                                                   Wc, bc, out, nullptr, N);
}

// Round 10
// 491.720 us; speedup vs baseline: 2.6814x; 1.4476x over previous
//
#include <hip/hip_runtime.h>

// FraudGNN: 2-layer GraphSAGE (mean agg) + fused linear classifier.
// CSR built per launch via 2-pass bucketed counting sort (no global atomics).
// Aggregation: bf16 feature gathers (halves random-gather traffic).
// Linear layers: bf16 MFMA GEMM (f32 accum), LDS-free, direct fragment loads.
// The f32 VALU GEMM was latency-bound at 17% occupancy (154us/layer vs 42us
// FMA floor); MFMA removes the VALU work and the 50KB LDS residency cap.

#define CHUNK 32768  // edges per sort block

typedef __attribute__((ext_vector_type(8))) short bf16x8;
typedef __attribute__((ext_vector_type(4))) float f32x4;

__device__ __forceinline__ unsigned bf16rne(float f) {
  unsigned u = __float_as_uint(f);
  return (u + 0x7fffu + ((u >> 16) & 1u)) >> 16;
}

// ---- pass 1: per-chunk bucket histogram, bucket = dst >> 8 ----
__global__ __launch_bounds__(256) void hist_kernel(const int* __restrict__ dst,
                                                   int* __restrict__ hist,
                                                   int E, int KB, int B) {
  __shared__ int h[512];
  int b = blockIdx.x, t = threadIdx.x;
  for (int k = t; k < KB; k += 256) h[k] = 0;
  __syncthreads();
  int base = b * CHUNK;
  int lim = E - base; if (lim > CHUNK) lim = CHUNK;
  const int4* d4 = (const int4*)(dst + base);
  int n4 = lim >> 2;
  for (int j = t; j < n4; j += 256) {
    int4 d = d4[j];
    atomicAdd(&h[((unsigned)d.x) >> 8], 1);
    atomicAdd(&h[((unsigned)d.y) >> 8], 1);
    atomicAdd(&h[((unsigned)d.z) >> 8], 1);
    atomicAdd(&h[((unsigned)d.w) >> 8], 1);
  }
  for (int i = (lim & ~3) + t; i < lim; i += 256)
    atomicAdd(&h[((unsigned)dst[base + i]) >> 8], 1);
  __syncthreads();
  for (int k = t; k < KB; k += 256) hist[k * B + b] = h[k];
}

// ---- scan phase A: per-1024-block sums ----
__global__ __launch_bounds__(256) void blocksum_kernel(const int* __restrict__ v,
                                                       int* __restrict__ bsum, int n) {
  __shared__ int ws[4];
  int b = blockIdx.x, t = threadIdx.x;
  int base = b * 1024;
  int s = 0;
#pragma unroll
  for (int j = 0; j < 4; ++j) {
    int i = base + t + j * 256;
    if (i < n) s += v[i];
  }
#pragma unroll
  for (int d = 32; d > 0; d >>= 1) s += __shfl_down(s, d);
  if ((t & 63) == 0) ws[t >> 6] = s;
  __syncthreads();
  if (t == 0) bsum[b] = ws[0] + ws[1] + ws[2] + ws[3];
}

// ---- scan phase B: exclusive scan of up to 128 block sums, single wave ----
__global__ __launch_bounds__(64) void scan_bsums_kernel(const int* __restrict__ bsum,
                                                        int* __restrict__ boff, int nb) {
  int l = threadIdx.x;
  int v0 = (l < nb) ? bsum[l] : 0;
  int v1 = (l + 64 < nb) ? bsum[l + 64] : 0;
  int s0 = v0, s1 = v1;
#pragma unroll
  for (int d = 1; d < 64; d <<= 1) { int o = __shfl_up(s0, d); if (l >= d) s0 += o; }
  int tot0 = __shfl(s0, 63);
#pragma unroll
  for (int d = 1; d < 64; d <<= 1) { int o = __shfl_up(s1, d); if (l >= d) s1 += o; }
  s1 += tot0;
  if (l < nb) boff[l] = s0 - v0;
  if (l + 64 < nb) boff[l + 64] = s1 - v1;
}

// ---- scan phase C: final exclusive scan ----
__global__ __launch_bounds__(1024) void finalize_scan_kernel(const int* __restrict__ v,
                                                             const int* __restrict__ boff,
                                                             int* __restrict__ off, int M) {
  __shared__ int wsum[16];
  int b = blockIdx.x, t = threadIdx.x;
  int lane = t & 63, wid = t >> 6;
  int gi = b * 1024 + t;
  int d = (gi < M) ? v[gi] : 0;
  int ws = d;
#pragma unroll
  for (int dd = 1; dd < 64; dd <<= 1) { int o = __shfl_up(ws, dd); if (lane >= dd) ws += o; }
  if (lane == 63) wsum[wid] = ws;
  __syncthreads();
  if (wid == 0 && lane < 16) {
    int x = wsum[lane];
#pragma unroll
    for (int dd = 1; dd < 16; dd <<= 1) { int o = __shfl_up(x, dd); if (lane >= dd) x += o; }
    wsum[lane] = x;
  }
  __syncthreads();
  int wbase = (wid == 0) ? 0 : wsum[wid - 1];
  if (gi < M) off[gi] = boff[b] + wbase + ws - d;
}

// ---- pass 3: scatter packed (src | dstLow<<24) into per-(block,bucket) cells ----
__global__ __launch_bounds__(256) void scatter_kernel(const int* __restrict__ src,
                                                      const int* __restrict__ dst,
                                                      const int* __restrict__ off,
                                                      int* __restrict__ buf,
                                                      int E, int KB, int B) {
  __shared__ int cur[512];
  int b = blockIdx.x, t = threadIdx.x;
  for (int k = t; k < KB; k += 256) cur[k] = off[k * B + b];
  __syncthreads();
  int base = b * CHUNK;
  int lim = E - base; if (lim > CHUNK) lim = CHUNK;
  const int4* s4 = (const int4*)(src + base);
  const int4* d4 = (const int4*)(dst + base);
  int n4 = lim >> 2;
  for (int j = t; j < n4; j += 256) {
    int4 s = s4[j];
    int4 d = d4[j];
    int p;
    p = atomicAdd(&cur[((unsigned)d.x) >> 8], 1); buf[p] = s.x | ((d.x & 255) << 24);
    p = atomicAdd(&cur[((unsigned)d.y) >> 8], 1); buf[p] = s.y | ((d.y & 255) << 24);
    p = atomicAdd(&cur[((unsigned)d.z) >> 8], 1); buf[p] = s.z | ((d.z & 255) << 24);
    p = atomicAdd(&cur[((unsigned)d.w) >> 8], 1); buf[p] = s.w | ((d.w & 255) << 24);
  }
  for (int i = (lim & ~3) + t; i < lim; i += 256) {
    int s = src[base + i], d = dst[base + i];
    int p = atomicAdd(&cur[((unsigned)d) >> 8], 1);
    buf[p] = s | ((d & 255) << 24);
  }
}

// ---- pass 4: per-bucket counting sort in LDS; writes rowptr/rdeg + sorted srcs ----
__global__ __launch_bounds__(256) void bucket_kernel(const int* __restrict__ off,
                                                     int* __restrict__ buf,
                                                     int* __restrict__ rowptr,
                                                     float* __restrict__ rdeg,
                                                     int N, int E, int KB, int B) {
  __shared__ int stage[12288];
  __shared__ int cnt[256], cur2[256];
  int k = blockIdx.x, t = threadIdx.x;
  int lo = off[k * B];
  int hi = (k == KB - 1) ? E : off[(k + 1) * B];
  int m = hi - lo; if (m > 12288) m = 12288;  // statistically unreachable
  for (int i = t; i < m; i += 256) stage[i] = buf[lo + i];
  cnt[t] = 0;
  __syncthreads();
  for (int i = t; i < m; i += 256) atomicAdd(&cnt[((unsigned)stage[i]) >> 24], 1);
  __syncthreads();
  if (t < 64) {
    int c[4], e[4];
    int i0 = t * 4;
    c[0] = cnt[i0]; c[1] = cnt[i0 + 1]; c[2] = cnt[i0 + 2]; c[3] = cnt[i0 + 3];
    int local = c[0] + c[1] + c[2] + c[3];
    int ws = local;
#pragma unroll
    for (int d = 1; d < 64; d <<= 1) { int o = __shfl_up(ws, d); if (t >= d) ws += o; }
    e[0] = ws - local;
    e[1] = e[0] + c[0];
    e[2] = e[1] + c[1];
    e[3] = e[2] + c[2];
#pragma unroll
    for (int j = 0; j < 4; ++j) {
      cur2[i0 + j] = e[j];
      int node = k * 256 + i0 + j;
      if (node < N) {
        rowptr[node] = lo + e[j];
        rdeg[node] = 1.0f / (float)(c[j] > 1 ? c[j] : 1);
      }
    }
  }
  __syncthreads();
  for (int i = t; i < m; i += 256) {
    int v = stage[i];
    int d = ((unsigned)v) >> 24;
    int p = atomicAdd(&cur2[d], 1);
    buf[lo + p] = v & 0xFFFFFF;
  }
  if (k == 0 && t == 0) rowptr[N] = E;
}

// ---- f32 -> bf16 (RNE) conversion, 8 elems/thread ----
__global__ __launch_bounds__(256) void conv_kernel(const float* __restrict__ in,
                                                   unsigned short* __restrict__ out,
                                                   int n8) {  // n/8
  int i = blockIdx.x * blockDim.x + threadIdx.x;
  int stride = gridDim.x * blockDim.x;
  for (; i < n8; i += stride) {
    float4 a = ((const float4*)in)[i * 2];
    float4 b = ((const float4*)in)[i * 2 + 1];
    int4 o;
    o.x = (int)(bf16rne(a.x) | (bf16rne(a.y) << 16));
    o.y = (int)(bf16rne(a.z) | (bf16rne(a.w) << 16));
    o.z = (int)(bf16rne(b.x) | (bf16rne(b.y) << 16));
    o.w = (int)(bf16rne(b.z) | (bf16rne(b.w) << 16));
    ((int4*)out)[i] = o;
  }
}

// ---- mean aggregation from bf16 rows, bf16 output ----
// 16-lane groups: lane = g*16+f; group g takes edges e ≡ g (mod 4),
// lane f loads int4 = 8 bf16 features. Group-reduce via shfl_xor(16/32).
__global__ __launch_bounds__(256) void agg_kernel(const unsigned short* __restrict__ inb,
                                                  const int* __restrict__ srcs,
                                                  const int* __restrict__ rowptr,
                                                  const float* __restrict__ rdeg,
                                                  unsigned short* __restrict__ outb, int n) {
  int node = blockIdx.x * 4 + (threadIdx.x >> 6);
  if (node >= n) return;
  int lane = threadIdx.x & 63;
  int g = lane >> 4;
  int f = lane & 15;
  int s0 = rowptr[node], s1 = rowptr[node + 1];
  float acc[8];
#pragma unroll
  for (int j = 0; j < 8; ++j) acc[j] = 0.f;

  int e = s0 + g;
  for (; e + 4 < s1; e += 8) {
    int a = srcs[e], b = srcs[e + 4];
    int4 va = ((const int4*)(inb + (size_t)a * 128))[f];
    int4 vb = ((const int4*)(inb + (size_t)b * 128))[f];
#pragma unroll
    for (int j = 0; j < 4; ++j) {
      int w = (&va.x)[j];
      acc[j * 2]     += __uint_as_float(((unsigned)w) << 16);
      acc[j * 2 + 1] += __uint_as_float(((unsigned)w) & 0xffff0000u);
    }
#pragma unroll
    for (int j = 0; j < 4; ++j) {
      int w = (&vb.x)[j];
      acc[j * 2]     += __uint_as_float(((unsigned)w) << 16);
      acc[j * 2 + 1] += __uint_as_float(((unsigned)w) & 0xffff0000u);
    }
  }
  if (e < s1) {
    int4 v = ((const int4*)(inb + (size_t)srcs[e] * 128))[f];
#pragma unroll
    for (int j = 0; j < 4; ++j) {
      int w = (&v.x)[j];
      acc[j * 2]     += __uint_as_float(((unsigned)w) << 16);
      acc[j * 2 + 1] += __uint_as_float(((unsigned)w) & 0xffff0000u);
    }
  }
#pragma unroll
  for (int j = 0; j < 8; ++j) {
    acc[j] += __shfl_xor(acc[j], 16);
    acc[j] += __shfl_xor(acc[j], 32);
  }
  if (lane < 16) {
    float r = rdeg[node];
    int4 ob;
    ob.x = (int)(bf16rne(acc[0] * r) | (bf16rne(acc[1] * r) << 16));
    ob.y = (int)(bf16rne(acc[2] * r) | (bf16rne(acc[3] * r) << 16));
    ob.z = (int)(bf16rne(acc[4] * r) | (bf16rne(acc[5] * r) << 16));
    ob.w = (int)(bf16rne(acc[6] * r) | (bf16rne(acc[7] * r) << 16));
    *(int4*)(outb + (size_t)node * 128 + f * 8) = ob;
  }
}

// ---- MFMA layer GEMM: relu([agg|x] @ [Wl|Wr]^T + bl), opt. classifier ----
// LDS-free. 256 thr = 4 waves; block tile 128 rows x 128 cols; each wave
// 32 rows = 2 m-frags x 8 n-frags of 16x16, K=256 in 8 steps of 32.
// v_mfma_f32_16x16x32_bf16 layouts: A/B lane holds 8 consecutive k
// (k = (lane>>4)*8 + j) for row/col = lane&15; C/D col=lane&15,
// row=(lane>>4)*4+reg (m89-verified).
template <bool FUSE_CLS>
__global__ __launch_bounds__(256) void mfma_lin_kernel(
    const unsigned short* __restrict__ Aagg,   // [n][128] bf16 (mean-agg)
    const unsigned short* __restrict__ Ax,     // [n][128] bf16 (x or h1)
    const unsigned short* __restrict__ Wlb,    // [128][128] bf16
    const unsigned short* __restrict__ Wrb,    // [128][128] bf16
    const float* __restrict__ bl,
    const float* __restrict__ Wc, const float* __restrict__ bc,
    unsigned short* __restrict__ outb,         // !FUSE: [n][128] bf16 out
    float* __restrict__ out,                   // FUSE: [n] logits
    int n) {
  int wv = threadIdx.x >> 6;
  int lane = threadIdx.x & 63;
  int cl = lane & 15;
  int kg = lane >> 4;
  int r0 = blockIdx.x * 128 + wv * 32;

  float bias[8];
#pragma unroll
  for (int nf = 0; nf < 8; ++nf) bias[nf] = bl[nf * 16 + cl];

  f32x4 acc[2][8];
#pragma unroll
  for (int mf = 0; mf < 2; ++mf)
#pragma unroll
    for (int nf = 0; nf < 8; ++nf) acc[mf][nf] = (f32x4){0.f, 0.f, 0.f, 0.f};

  int ra = r0 + cl;       if (ra >= n) ra = n - 1;
  int rb = r0 + 16 + cl;  if (rb >= n) rb = n - 1;

#pragma unroll
  for (int ks = 0; ks < 8; ++ks) {
    const unsigned short* As = (ks < 4) ? Aagg : Ax;
    const unsigned short* Ws = (ks < 4) ? Wlb : Wrb;
    int kl = (ks & 3) * 32 + kg * 8;
    bf16x8 a0 = *(const bf16x8*)(As + (size_t)ra * 128 + kl);
    bf16x8 a1 = *(const bf16x8*)(As + (size_t)rb * 128 + kl);
    bf16x8 b[8];
#pragma unroll
    for (int nf = 0; nf < 8; ++nf)
      b[nf] = *(const bf16x8*)(Ws + (size_t)(nf * 16 + cl) * 128 + kl);
#pragma unroll
    for (int nf = 0; nf < 8; ++nf) {
      acc[0][nf] = __builtin_amdgcn_mfma_f32_16x16x32_bf16(a0, b[nf], acc[0][nf], 0, 0, 0);
      acc[1][nf] = __builtin_amdgcn_mfma_f32_16x16x32_bf16(a1, b[nf], acc[1][nf], 0, 0, 0);
    }
  }

  if (FUSE_CLS) {
    float wc[8];
#pragma unroll
    for (int nf = 0; nf < 8; ++nf) wc[nf] = Wc[nf * 16 + cl];
    float bc0 = bc[0];
#pragma unroll
    for (int mf = 0; mf < 2; ++mf)
#pragma unroll
      for (int r = 0; r < 4; ++r) {
        float p = 0.f;
#pragma unroll
        for (int nf = 0; nf < 8; ++nf)
          p += fmaxf(acc[mf][nf][r] + bias[nf], 0.f) * wc[nf];
#pragma unroll
        for (int d = 1; d < 16; d <<= 1) p += __shfl_xor(p, d);
        int row = r0 + mf * 16 + kg * 4 + r;
        if (cl == 0 && row < n) out[row] = p + bc0;
      }
  } else {
#pragma unroll
    for (int mf = 0; mf < 2; ++mf)
#pragma unroll
      for (int r = 0; r < 4; ++r) {
        int row = r0 + mf * 16 + kg * 4 + r;
        if (row < n) {
#pragma unroll
          for (int nf = 0; nf < 8; ++nf) {
            float v = fmaxf(acc[mf][nf][r] + bias[nf], 0.f);
            outb[(size_t)row * 128 + nf * 16 + cl] = (unsigned short)bf16rne(v);
          }
        }
      }
  }
}

extern "C" void kernel_launch(void* const* d_in, const int* in_sizes, int n_in,
                              void* d_out, int out_size, void* d_ws, size_t ws_size,
                              hipStream_t stream) {
  const float* x   = (const float*)d_in[0];
  const int*   ei  = (const int*)d_in[1];
  const float* Wl1 = (const float*)d_in[2];
  const float* bl1 = (const float*)d_in[3];
  const float* Wr1 = (const float*)d_in[4];
  const float* Wl2 = (const float*)d_in[5];
  const float* bl2 = (const float*)d_in[6];
  const float* Wr2 = (const float*)d_in[7];
  const float* Wc  = (const float*)d_in[8];
  const float* bc  = (const float*)d_in[9];
  float* out = (float*)d_out;

  const int N = in_sizes[0] / 128;
  const int E = in_sizes[1] / 2;
  const int* src = ei;
  const int* dst = ei + E;

  const int KB = (N + 255) >> 8;            // buckets (391)
  const int B  = (E + CHUNK - 1) / CHUNK;   // sort blocks (98)
  const int M  = KB * B;                    // histogram cells
  const int NB = (M + 1023) / 1024;         // scan blocks

  // workspace carve-up (~92 MB total)
  char* w = (char*)d_ws;
  auto alloc = [&](size_t bytes) { void* p = (void*)w; w += (bytes + 255) & ~(size_t)255; return p; };
  int*   hist   = (int*)alloc((size_t)M * 4);
  int*   off    = (int*)alloc((size_t)M * 4);
  int*   bsum   = (int*)alloc((size_t)NB * 4);
  int*   boff   = (int*)alloc((size_t)NB * 4);
  int*   buf    = (int*)alloc((size_t)E * 4);       // packed, then sorted srcs
  int*   rowptr = (int*)alloc((size_t)(N + 1) * 4);
  float* rdeg   = (float*)alloc((size_t)N * 4);
  unsigned short* xb   = (unsigned short*)alloc((size_t)N * 128 * 2);
  unsigned short* h1b  = (unsigned short*)alloc((size_t)N * 128 * 2);
  unsigned short* aggb = (unsigned short*)alloc((size_t)N * 128 * 2);
  unsigned short* Wl1b = (unsigned short*)alloc(128 * 128 * 2);
  unsigned short* Wr1b = (unsigned short*)alloc(128 * 128 * 2);
  unsigned short* Wl2b = (unsigned short*)alloc(128 * 128 * 2);
  unsigned short* Wr2b = (unsigned short*)alloc(128 * 128 * 2);

  // CSR build (bucketed counting sort, no global atomics)
  hist_kernel<<<B, 256, 0, stream>>>(dst, hist, E, KB, B);
  blocksum_kernel<<<NB, 256, 0, stream>>>(hist, bsum, M);
  scan_bsums_kernel<<<1, 64, 0, stream>>>(bsum, boff, NB);
  finalize_scan_kernel<<<NB, 1024, 0, stream>>>(hist, boff, off, M);
  scatter_kernel<<<B, 256, 0, stream>>>(src, dst, off, buf, E, KB, B);
  bucket_kernel<<<KB, 256, 0, stream>>>(off, buf, rowptr, rdeg, N, E, KB, B);
  // bf16 copies: features + weights
  conv_kernel<<<1024, 256, 0, stream>>>(x, xb, N * 128 / 8);
  conv_kernel<<<16, 256, 0, stream>>>(Wl1, Wl1b, 128 * 128 / 8);
  conv_kernel<<<16, 256, 0, stream>>>(Wr1, Wr1b, 128 * 128 / 8);
  conv_kernel<<<16, 256, 0, stream>>>(Wl2, Wl2b, 128 * 128 / 8);
  conv_kernel<<<16, 256, 0, stream>>>(Wr2, Wr2b, 128 * 128 / 8);

  const int AGRID = (N + 3) / 4;
  const int LGRID = (N + 127) / 128;
  // layer 1
  agg_kernel<<<AGRID, 256, 0, stream>>>(xb, buf, rowptr, rdeg, aggb, N);
  mfma_lin_kernel<false><<<LGRID, 256, 0, stream>>>(aggb, xb, Wl1b, Wr1b, bl1,
                                                    nullptr, nullptr, h1b, nullptr, N);
  // layer 2 (+ fused classifier)
  agg_kernel<<<AGRID, 256, 0, stream>>>(h1b, buf, rowptr, rdeg, aggb, N);
  mfma_lin_kernel<true><<<LGRID, 256, 0, stream>>>(aggb, h1b, Wl2b, Wr2b, bl2,
                                                   Wc, bc, nullptr, out, N);
}